// Round 6
// baseline (1136.061 us; speedup 1.0000x reference)
//
#include <hip/hip_runtime.h>
#include <hip/hip_bf16.h>

#define B_   64
#define T_   512
#define N_   14
#define F_   16
#define H_   128
#define G4_  512
#define TCH  16     // timesteps staged per LDS chunk
#define MBLK 32     // sequences per block (2 groups of 16)
#define NBLK 28

typedef __attribute__((ext_vector_type(8))) short bfrag;  // 8 bf16
typedef __attribute__((ext_vector_type(4))) float facc;   // fp32 acc
typedef __attribute__((ext_vector_type(4))) int   v4i;    // i8x16 / i32x4

#define L2E   1.4426950408889634f
#define L2E2  2.8853900817779268f

// LDS byte offsets
#define SXA 0        // [16 tl][16 seq][32 k] bf16 (k>=16 zero) = 16 KB
#define SXB 16384
#define SHA 32768    // h8 group A: [16 seq][128] i8 = 2 KB (swizzled)
#define SHB 34816
#define LDSZ 36864

__device__ __forceinline__ short f2bf(float f) {
    unsigned u = __builtin_bit_cast(unsigned, f);
    return (short)((u + 0x7FFFu + ((u >> 16) & 1u)) >> 16);
}
__device__ __forceinline__ float bf2f(unsigned short s) {
    return __builtin_bit_cast(float, (unsigned)s << 16);
}
__device__ __forceinline__ unsigned cvt_pk_bf16(float a, float b) {
    unsigned r;
    asm("v_cvt_pk_bf16_f32 %0, %1, %2" : "=v"(r) : "v"(a), "v"(b));
    return r;
}
// i8 MFMA via inline asm (signature-proof; deps tracked through operands).
__device__ __forceinline__ v4i mfma_i8(v4i a, v4i b, v4i c) {
    v4i d;
    asm("v_mfma_i32_16x16x64_i8 %0, %1, %2, %3"
        : "=&v"(d) : "v"(a), "v"(b), "v"(c));
    return d;
}
// lgkm-only barrier: keeps global prefetch loads in flight across barriers.
__device__ __forceinline__ void bar() {
    asm volatile("s_waitcnt lgkmcnt(0)" ::: "memory");
    __builtin_amdgcn_s_barrier();
    asm volatile("" ::: "memory");
}

// ---------------------------------------------------------------------------
// prep1: per-gate row-max of W_hh -> i8 scale; fused biases; all pre-scaled
// by log2(e) (2x for the g-gate section) so the epilogue uses native exp2.
// ---------------------------------------------------------------------------
__global__ void prep1_kernel(const float* __restrict__ W_hh,
                             const float* __restrict__ b_ih, const float* __restrict__ b_hh,
                             float* __restrict__ inv127, float* __restrict__ sw,
                             float* __restrict__ bias) {
    const int g = threadIdx.x;            // 0..511
    float mx = 0.0f;
    for (int k = 0; k < H_; ++k) mx = fmaxf(mx, fabsf(W_hh[g * H_ + k]));
    const float sc = (g >= 256 && g < 384) ? L2E2 : L2E;
    inv127[g] = 127.0f / mx;
    sw[g]     = mx * sc * (1.0f / 16129.0f);   // mx/127 * 1/127 * log2e-scale
    bias[g]   = (b_ih[g] + b_hh[g]) * sc;
}

// ---------------------------------------------------------------------------
// prep2: W_hh -> i8 (row-scaled); W_ih -> bf16 (log2e-scaled, K padded 16->32)
// ---------------------------------------------------------------------------
__global__ void prep2_kernel(const float* __restrict__ W_hh, const float* __restrict__ W_ih,
                             const float* __restrict__ inv127,
                             signed char* __restrict__ w8, short* __restrict__ wih_bf) {
    const int i = blockIdx.x * blockDim.x + threadIdx.x;   // 0..65535
    if (i < G4_ * H_)
        w8[i] = (signed char)(int)rintf(W_hh[i] * inv127[i >> 7]);
    if (i < G4_ * 32) {
        const int n = i >> 5, k = i & 31;
        const float sc = (n >= 256 && n < 384) ? L2E2 : L2E;
        wih_bf[i] = (k < F_) ? f2bf(W_ih[n * F_ + k] * sc) : (short)0;
    }
}

// ---------------------------------------------------------------------------
// Half-step: compute group M's gates (i8 MFMA K=64 x2 + bf16 x-MFMA), while
// finishing group O's previous step (epilogue on VALU/trans pipes) and
// writing O's h (i8) to LDS. Barrier follows at call site.
// ---------------------------------------------------------------------------
__device__ __forceinline__ void half_step(char* lds, int shR, int shW, int sx_addr,
    const v4i (&B8)[4][2], const bfrag (&Bx)[4], const facc (&bsp)[4],
    const float (&sw4)[4],
    v4i (&accM)[4], facc (&xaccM)[4],
    const v4i (&accO)[4], const facc (&xaccO)[4], float (&ccO)[4],
    int hoff0, int hoff1, const int (&stoff)[4])
{
    const v4i a0 = *(const v4i*)(lds + shR + hoff0);
    const v4i a1 = *(const v4i*)(lds + shR + hoff1);
    const bfrag ax = *(const bfrag*)(lds + sx_addr);

    const v4i z4 = (v4i){0, 0, 0, 0};
#pragma unroll
    for (int q = 0; q < 4; ++q) accM[q] = mfma_i8(a0, B8[q][0], z4);
#pragma unroll
    for (int q = 0; q < 4; ++q) accM[q] = mfma_i8(a1, B8[q][1], accM[q]);
#pragma unroll
    for (int q = 0; q < 4; ++q)
        xaccM[q] = __builtin_amdgcn_mfma_f32_16x16x32_bf16(ax, Bx[q], bsp[q], 0, 0, 0);

    // epilogue of the OTHER group's completed step (4 seq-rows per lane)
#pragma unroll
    for (int r = 0; r < 4; ++r) {
        const float z0 = (float)accO[0][r] * sw4[0] + xaccO[0][r];
        const float z1 = (float)accO[1][r] * sw4[1] + xaccO[1][r];
        const float z2 = (float)accO[2][r] * sw4[2] + xaccO[2][r];
        const float z3 = (float)accO[3][r] * sw4[3] + xaccO[3][r];
        const float ea = exp2f(-z0);
        const float ef = exp2f(-z1);
        const float eo = exp2f(-z3);
        const float eg = exp2f(-fabsf(z2));
        const float d1 = (1.0f + ea) * (1.0f + eg);
        const float d2 = 1.0f + ef;
        const float rP = __builtin_amdgcn_rcpf(d1 * d2);   // shared rcp
        const float ig = __builtin_copysignf((1.0f - eg) * (rP * d2), z2);
        ccO[r] = (rP * d1) * ccO[r] + ig;
        const float ec = exp2f(-L2E2 * fabsf(ccO[r]));
        const float hv = __builtin_copysignf(
            (1.0f - ec) * __builtin_amdgcn_rcpf((1.0f + eo) * (1.0f + ec)), ccO[r]);
        const int q8 = (int)rintf(hv * 127.0f);
        *(signed char*)(lds + shW + stoff[r]) = (signed char)q8;
    }
}

// ---------------------------------------------------------------------------
// LSTM: 28 blocks x 512 thr; block owns 32 seqs as two pipelined groups of 16.
// ---------------------------------------------------------------------------
__global__ __launch_bounds__(512, 2) void lstm_kernel(
    const float* __restrict__ x,            // [B, T, N, F] fp32
    const signed char* __restrict__ w8,     // [512][128] i8
    const short* __restrict__ wih_bf,       // [512][32] bf16
    const float* __restrict__ bias,         // [512] (log2e-scaled)
    const float* __restrict__ sw,           // [512] descale * log2e
    unsigned short* __restrict__ h_out)     // [896][128] bf16
{
    const int m0  = blockIdx.x * MBLK;
    const int tid = threadIdx.x;
    const int w   = tid >> 6, l = tid & 63;
    const int lr  = l & 15, lk = l >> 4;
    const int hcol = w * 16 + lr;

    __shared__ __align__(16) char lds[LDSZ];

    // ---- loop-invariant register state ----
    v4i   B8[4][2];
    bfrag Bx[4];
    facc  bsp[4];
    float sw4[4];
#pragma unroll
    for (int q = 0; q < 4; ++q) {
        const int n = q * H_ + hcol;
#pragma unroll
        for (int ks = 0; ks < 2; ++ks)
            B8[q][ks] = *(const v4i*)(w8 + n * 128 + ks * 64 + lk * 16);
        Bx[q] = *(const bfrag*)(wih_bf + n * 32 + lk * 8);
        const float b = bias[n];
        bsp[q] = (facc){b, b, b, b};
        sw4[q] = sw[n];
    }
#pragma unroll
    for (int q = 0; q < 4; ++q) {          // pin: forbid in-loop remat
        asm volatile("" : "+v"(B8[q][0]));
        asm volatile("" : "+v"(B8[q][1]));
        asm volatile("" : "+v"(Bx[q]));
        asm volatile("" : "+v"(bsp[q]));
    }

    // swizzled LDS offsets
    const int swzk = (lr & 7) << 4;
    const int hoff0 = (lr * 128 + lk * 16) ^ swzk;
    const int hoff1 = (lr * 128 + 64 + lk * 16) ^ swzk;
    const int xoff  = (lr * 64 + lk * 16) ^ swzk;
    int stoff[4];
#pragma unroll
    for (int r = 0; r < 4; ++r) {
        const int row = lk * 4 + r;
        stoff[r] = (row * 128 + hcol) ^ ((row & 7) << 4);
    }

    // staging ids: thread -> (tl, seq, kb-half) for both groups
    const int skb = tid & 1, sseq = (tid >> 1) & 15, stl = tid >> 5;
    const int seqA = m0 + sseq, seqB = seqA + 16;
    const int bbA = seqA / N_, nnA = seqA % N_;
    const int bbB = seqB / N_, nnB = seqB % N_;
    const float* xA = x + (((size_t)bbA * T_ + stl) * N_ + nnA) * F_ + skb * 8;
    const float* xB = x + (((size_t)bbB * T_ + stl) * N_ + nnB) * F_ + skb * 8;
    const int sbyte = (stl * 1024 + sseq * 64 + skb * 16) ^ ((sseq & 7) << 4);

    // ---- init: zero LDS (x pad + h=0), prefetch chunk 0 ----
    for (int i = tid; i < LDSZ / 4; i += 512) ((int*)lds)[i] = 0;
    float4 pA0 = *(const float4*)xA, pA1 = *(const float4*)(xA + 4);
    float4 pB0 = *(const float4*)xB, pB1 = *(const float4*)(xB + 4);
    bar();

    float ccA[4] = {0.f, 0.f, 0.f, 0.f}, ccB[4] = {0.f, 0.f, 0.f, 0.f};
    v4i  accA[4], accB[4];
    facc xaccA[4], xaccB[4];
#pragma unroll
    for (int q = 0; q < 4; ++q) {           // so epilogue_B(-1) writes h=0
        accB[q] = (v4i){0, 0, 0, 0};
        xaccB[q] = (facc){0.f, 0.f, 0.f, 0.f};
    }

#pragma unroll 1
    for (int chunk = 0; chunk < T_ / TCH; ++chunk) {
        // store staged x (sx idle between last read and this point)
        {
            uint4 oa, ob;
            oa.x = cvt_pk_bf16(pA0.x, pA0.y); oa.y = cvt_pk_bf16(pA0.z, pA0.w);
            oa.z = cvt_pk_bf16(pA1.x, pA1.y); oa.w = cvt_pk_bf16(pA1.z, pA1.w);
            ob.x = cvt_pk_bf16(pB0.x, pB0.y); ob.y = cvt_pk_bf16(pB0.z, pB0.w);
            ob.z = cvt_pk_bf16(pB1.x, pB1.y); ob.w = cvt_pk_bf16(pB1.z, pB1.w);
            *(uint4*)(lds + SXA + sbyte) = oa;
            *(uint4*)(lds + SXB + sbyte) = ob;
        }
        bar();

#pragma unroll 1
        for (int tl = 0; tl < TCH; ++tl) {
            if (tl == 8 && chunk + 1 < T_ / TCH) {   // prefetch next chunk
                xA += TCH * N_ * F_; xB += TCH * N_ * F_;
                pA0 = *(const float4*)xA; pA1 = *(const float4*)(xA + 4);
                pB0 = *(const float4*)xB; pB1 = *(const float4*)(xB + 4);
            }
            // half A: compute A(t), finish B(t-1) -> write hB
            half_step(lds, SHA, SHB, SXA + tl * 1024 + xoff,
                      B8, Bx, bsp, sw4, accA, xaccA, accB, xaccB, ccB,
                      hoff0, hoff1, stoff);
            bar();
            // half B: compute B(t), finish A(t) -> write hA
            half_step(lds, SHB, SHA, SXB + tl * 1024 + xoff,
                      B8, Bx, bsp, sw4, accB, xaccB, accA, xaccA, ccA,
                      hoff0, hoff1, stoff);
            bar();
        }
    }

    // drain: epilogue_B(511) -> write hB
#pragma unroll
    for (int r = 0; r < 4; ++r) {
        const float z0 = (float)accB[0][r] * sw4[0] + xaccB[0][r];
        const float z1 = (float)accB[1][r] * sw4[1] + xaccB[1][r];
        const float z2 = (float)accB[2][r] * sw4[2] + xaccB[2][r];
        const float z3 = (float)accB[3][r] * sw4[3] + xaccB[3][r];
        const float ea = exp2f(-z0), ef = exp2f(-z1), eo = exp2f(-z3);
        const float eg = exp2f(-fabsf(z2));
        const float d1 = (1.0f + ea) * (1.0f + eg), d2 = 1.0f + ef;
        const float rP = __builtin_amdgcn_rcpf(d1 * d2);
        const float ig = __builtin_copysignf((1.0f - eg) * (rP * d2), z2);
        ccB[r] = (rP * d1) * ccB[r] + ig;
        const float ec = exp2f(-L2E2 * fabsf(ccB[r]));
        const float hv = __builtin_copysignf(
            (1.0f - ec) * __builtin_amdgcn_rcpf((1.0f + eo) * (1.0f + ec)), ccB[r]);
        *(signed char*)(lds + SHB + stoff[r]) = (signed char)(int)rintf(hv * 127.0f);
    }
    bar();

    // readout: h8 -> bf16
    for (int e = tid; e < MBLK * H_; e += 512) {
        const int g = e >> 11, s = (e >> 7) & 15, c = e & 127;
        const int byte = (s * 128 + c) ^ ((s & 7) << 4);
        const signed char v = *(const signed char*)(lds + (g ? SHB : SHA) + byte);
        h_out[(size_t)(m0 + g * 16 + s) * H_ + c] = f2bf((float)v * (1.0f / 127.0f));
    }
}

// ---------------------------------------------------------------------------
// Head kernel: one block per batch element b. GCN + linears + sigmoid.
// ---------------------------------------------------------------------------
__global__ __launch_bounds__(256) void head_kernel(
    const float* __restrict__ adj,
    const float* __restrict__ W_gcn, const float* __restrict__ b_gcn,
    const float* __restrict__ W_out, const float* __restrict__ b_out,
    const float* __restrict__ W_lin1, const float* __restrict__ b_lin1,
    const unsigned short* __restrict__ h_in,   // [896][128] bf16
    float* __restrict__ out)                   // [B, 28]
{
    const int b   = blockIdx.x;
    const int tid = threadIdx.x;

    __shared__ float s_A[N_][N_];
    __shared__ float s_d[N_];
    __shared__ float s_h[N_][H_];
    __shared__ float s_xg[N_][H_];
    __shared__ float s_g1[N_][64];
    __shared__ float s_s[N_];

    for (int idx = tid; idx < N_ * H_; idx += 256)
        s_h[idx >> 7][idx & 127] = bf2f(h_in[(size_t)b * N_ * H_ + idx]);

    if (tid < N_) {
        float sum = 0.0f;
        for (int j = 0; j < N_; ++j)
            sum += adj[tid * N_ + j] + (tid == j ? 1.0f : 0.0f);
        s_d[tid] = rsqrtf(sum);
    }
    __syncthreads();

    if (tid < N_ * N_) {
        const int i = tid / N_, j = tid % N_;
        const float a = adj[i * N_ + j] + (i == j ? 1.0f : 0.0f);
        s_A[i][j] = s_d[i] * a * s_d[j];
    }
    __syncthreads();

    for (int idx = tid; idx < N_ * H_; idx += 256) {
        const int i = idx >> 7, k = idx & 127;
        float acc = 0.0f;
#pragma unroll
        for (int j = 0; j < N_; ++j) acc += s_A[i][j] * s_h[j][k];
        s_xg[i][k] = acc;
    }
    __syncthreads();

    for (int idx = tid; idx < N_ * 64; idx += 256) {
        const int i = idx >> 6, q = idx & 63;
        float a0 = 0.f, a1 = 0.f, a2 = 0.f, a3 = 0.f;
#pragma unroll
        for (int k = 0; k < H_; k += 4) {
            a0 += s_xg[i][k+0] * W_gcn[q * H_ + k+0];
            a1 += s_xg[i][k+1] * W_gcn[q * H_ + k+1];
            a2 += s_xg[i][k+2] * W_gcn[q * H_ + k+2];
            a3 += s_xg[i][k+3] * W_gcn[q * H_ + k+3];
        }
        const float acc = b_gcn[q] + ((a0 + a1) + (a2 + a3));
        s_g1[i][q] = fmaxf(acc, 0.0f);
    }
    __syncthreads();

    if (tid < N_) {
        float acc = b_out[0];
#pragma unroll
        for (int q = 0; q < 64; ++q) acc += s_g1[tid][q] * W_out[q];
        s_s[tid] = acc;
    }
    __syncthreads();

    if (tid < 28) {
        float acc = b_lin1[tid];
#pragma unroll
        for (int i = 0; i < N_; ++i) acc += s_s[i] * W_lin1[tid * N_ + i];
        out[b * 28 + tid] = 1.0f / (1.0f + __expf(-acc));
    }
}

extern "C" void kernel_launch(void* const* d_in, const int* in_sizes, int n_in,
                              void* d_out, int out_size, void* d_ws, size_t ws_size,
                              hipStream_t stream) {
    const float* x      = (const float*)d_in[0];
    const float* adj    = (const float*)d_in[1];
    const float* W_ih   = (const float*)d_in[2];
    const float* W_hh   = (const float*)d_in[3];
    const float* b_ih   = (const float*)d_in[4];
    const float* b_hh   = (const float*)d_in[5];
    const float* W_gcn  = (const float*)d_in[6];
    const float* b_gcn  = (const float*)d_in[7];
    const float* W_out  = (const float*)d_in[8];
    const float* b_out  = (const float*)d_in[9];
    const float* W_lin1 = (const float*)d_in[10];
    const float* b_lin1 = (const float*)d_in[11];
    float* out = (float*)d_out;

    // workspace layout (bytes): total 333824
    char* ws = (char*)d_ws;
    signed char*    w8     = (signed char*)(ws);              // 512*128   =  65536
    short*          wih_bf = (short*)(ws + 65536);            // 512*32*2  =  32768
    float*          bias   = (float*)(ws + 98304);            // 512*4     =   2048
    float*          sw     = (float*)(ws + 100352);           // 512*4     =   2048
    float*          inv127 = (float*)(ws + 102400);           // 512*4     =   2048
    unsigned short* h_last = (unsigned short*)(ws + 104448);  // 896*128*2 = 229376

    prep1_kernel<<<1, 512, 0, stream>>>(W_hh, b_ih, b_hh, inv127, sw, bias);
    prep2_kernel<<<128, 512, 0, stream>>>(W_hh, W_ih, inv127, w8, wih_bf);
    lstm_kernel<<<NBLK, 512, 0, stream>>>(x, w8, wih_bf, bias, sw, h_last);
    head_kernel<<<B_, 256, 0, stream>>>(adj, W_gcn, b_gcn, W_out, b_out,
                                        W_lin1, b_lin1, h_last, out);
}

// Round 7
// 760.263 us; speedup vs baseline: 1.4943x; 1.4943x over previous
//
#include <hip/hip_runtime.h>
#include <hip/hip_bf16.h>

#define B_   64
#define T_   512
#define N_   14
#define F_   16
#define H_   128
#define G4_  512
#define TCH  64     // timesteps staged per LDS chunk
#define MBLK 8      // sequences per block (2 groups of 4)
#define NBLK 112

typedef __attribute__((ext_vector_type(8))) short bfrag;  // 8 bf16
typedef __attribute__((ext_vector_type(4))) float facc;   // fp32 acc
typedef __attribute__((ext_vector_type(4))) int   v4i;    // i8x16 / i32x4

#define L2E   1.4426950408889634f
#define L2E2  2.8853900817779268f

// LDS byte offsets
#define SXA 0        // x group A: [64 tl][4 seq][32 k] bf16 (k>=16 zero) = 16 KB
#define SXB 16384
#define SHA 32768    // h8 group A: [16 rows][128] i8 (rows 0-3 live, rest 0)
#define SHB 34816
#define LDSZ 36864

__device__ __forceinline__ short f2bf(float f) {
    unsigned u = __builtin_bit_cast(unsigned, f);
    return (short)((u + 0x7FFFu + ((u >> 16) & 1u)) >> 16);
}
__device__ __forceinline__ float bf2f(unsigned short s) {
    return __builtin_bit_cast(float, (unsigned)s << 16);
}
__device__ __forceinline__ unsigned cvt_pk_bf16(float a, float b) {
    unsigned r;
    asm("v_cvt_pk_bf16_f32 %0, %1, %2" : "=v"(r) : "v"(a), "v"(b));
    return r;
}
// i8 MFMA via inline asm (round-6 validated).
__device__ __forceinline__ v4i mfma_i8(v4i a, v4i b, v4i c) {
    v4i d;
    asm("v_mfma_i32_16x16x64_i8 %0, %1, %2, %3"
        : "=&v"(d) : "v"(a), "v"(b), "v"(c));
    return d;
}
// lgkm-only barrier: global prefetch loads stay in flight across barriers.
__device__ __forceinline__ void bar() {
    asm volatile("s_waitcnt lgkmcnt(0)" ::: "memory");
    __builtin_amdgcn_s_barrier();
    asm volatile("" ::: "memory");
}

// ---------------------------------------------------------------------------
// prep1: per-gate-row max of W_hh -> i8 scale; fused biases; log2e pre-scale
// (2x for the g-gate section) so the epilogue uses native exp2.
// ---------------------------------------------------------------------------
__global__ void prep1_kernel(const float* __restrict__ W_hh,
                             const float* __restrict__ b_ih, const float* __restrict__ b_hh,
                             float* __restrict__ inv127, float* __restrict__ sw,
                             float* __restrict__ bias) {
    const int g = threadIdx.x;            // 0..511
    float mx = 0.0f;
    for (int k = 0; k < H_; ++k) mx = fmaxf(mx, fabsf(W_hh[g * H_ + k]));
    const float sc = (g >= 256 && g < 384) ? L2E2 : L2E;
    inv127[g] = 127.0f / mx;
    sw[g]     = mx * sc * (1.0f / 16129.0f);   // mx/127 * 1/127 * log2e-scale
    bias[g]   = (b_ih[g] + b_hh[g]) * sc;
}

// ---------------------------------------------------------------------------
// prep2: W_hh -> i8 (row-scaled); W_ih -> bf16 (log2e-scaled, K padded 16->32)
// ---------------------------------------------------------------------------
__global__ void prep2_kernel(const float* __restrict__ W_hh, const float* __restrict__ W_ih,
                             const float* __restrict__ inv127,
                             signed char* __restrict__ w8, short* __restrict__ wih_bf) {
    const int i = blockIdx.x * blockDim.x + threadIdx.x;   // 0..65535
    if (i < G4_ * H_)
        w8[i] = (signed char)(int)rintf(W_hh[i] * inv127[i >> 7]);
    if (i < G4_ * 32) {
        const int n = i >> 5, k = i & 31;
        const float sc = (n >= 256 && n < 384) ? L2E2 : L2E;
        wih_bf[i] = (k < F_) ? f2bf(W_ih[n * F_ + k] * sc) : (short)0;
    }
}

// ---------------------------------------------------------------------------
// Spread-epilogue for one group: combine i32 acc (descale) + xacc on the
// source lanes, shuffle-spread to 1 element/lane, gate math, write h8.
// ---------------------------------------------------------------------------
__device__ __forceinline__ void epi_spread(char* lds, int shW,
    const v4i (&accO)[4], const facc (&xaccO)[4], const float (&sw4)[4],
    float& ccO, int stoff, int lrsrc, bool b0, bool b1)
{
    float z[4];
#pragma unroll
    for (int q = 0; q < 4; ++q) {
        const float z0 = (float)accO[q][0] * sw4[q] + xaccO[q][0];
        const float z1 = (float)accO[q][1] * sw4[q] + xaccO[q][1];
        const float z2 = (float)accO[q][2] * sw4[q] + xaccO[q][2];
        const float z3 = (float)accO[q][3] * sw4[q] + xaccO[q][3];
        const float s0 = __shfl(z0, lrsrc);
        const float s1 = __shfl(z1, lrsrc);
        const float s2 = __shfl(z2, lrsrc);
        const float s3 = __shfl(z3, lrsrc);
        const float t01 = b0 ? s1 : s0;
        const float t23 = b0 ? s3 : s2;
        z[q] = b1 ? t23 : t01;
    }
    const float ea = exp2f(-z[0]);
    const float ef = exp2f(-z[1]);
    const float eo = exp2f(-z[3]);
    const float eg = exp2f(-fabsf(z[2]));
    const float d1 = (1.0f + ea) * (1.0f + eg);
    const float d2 = 1.0f + ef;
    const float rP = __builtin_amdgcn_rcpf(d1 * d2);       // shared rcp
    const float ig = __builtin_copysignf((1.0f - eg) * (rP * d2), z[2]);
    ccO = (rP * d1) * ccO + ig;
    const float ec = exp2f(-L2E2 * fabsf(ccO));
    const float hv = __builtin_copysignf(
        (1.0f - ec) * __builtin_amdgcn_rcpf((1.0f + eo) * (1.0f + ec)), ccO);
    *(signed char*)(lds + shW + stoff) = (signed char)(int)rintf(hv * 127.0f);
}

// ---------------------------------------------------------------------------
// Half-step: compute group M's gates (2 i8 MFMAs + 1 bf16 x-MFMA per gate)
// while finishing group O's step (spread epilogue on VALU/trans pipes).
// ---------------------------------------------------------------------------
__device__ __forceinline__ void half_step(char* lds, int shR, int shW, int sx_addr,
    const v4i (&B8)[4][2], const bfrag (&Bx)[4], const facc (&bsp)[4],
    const float (&sw4)[4],
    v4i (&accM)[4], facc (&xaccM)[4],
    const v4i (&accO)[4], const facc (&xaccO)[4], float& ccO,
    int hoff0, int hoff1, int stoff, int lrsrc, bool b0, bool b1)
{
    const v4i a0 = *(const v4i*)(lds + shR + hoff0);
    const v4i a1 = *(const v4i*)(lds + shR + hoff1);
    const bfrag ax = *(const bfrag*)(lds + sx_addr);

    const v4i z4 = (v4i){0, 0, 0, 0};
#pragma unroll
    for (int q = 0; q < 4; ++q) accM[q] = mfma_i8(a0, B8[q][0], z4);
#pragma unroll
    for (int q = 0; q < 4; ++q) accM[q] = mfma_i8(a1, B8[q][1], accM[q]);
#pragma unroll
    for (int q = 0; q < 4; ++q)
        xaccM[q] = __builtin_amdgcn_mfma_f32_16x16x32_bf16(ax, Bx[q], bsp[q], 0, 0, 0);

    epi_spread(lds, shW, accO, xaccO, sw4, ccO, stoff, lrsrc, b0, b1);
}

// ---------------------------------------------------------------------------
// LSTM: 112 blocks x 512 thr; block owns 8 seqs as two pipelined groups of 4.
// Wave w owns gate-cols {q*128 + 16w .. +16} for all gates; 1-elem epilogue.
// ---------------------------------------------------------------------------
__global__ __launch_bounds__(512, 1) void lstm_kernel(
    const float* __restrict__ x,            // [B, T, N, F] fp32
    const signed char* __restrict__ w8,     // [512][128] i8
    const short* __restrict__ wih_bf,       // [512][32] bf16
    const float* __restrict__ bias,         // [512] (log2e-scaled)
    const float* __restrict__ sw,           // [512] descale * log2e
    unsigned short* __restrict__ h_out)     // [896][128] bf16
{
    const int m0  = blockIdx.x * MBLK;
    const int tid = threadIdx.x;
    const int w   = tid >> 6, l = tid & 63;
    const int lr  = l & 15, lk = l >> 4;
    const int hcol = w * 16 + lr;

    __shared__ __align__(16) char lds[LDSZ];

    // ---- loop-invariant register state ----
    v4i   B8[4][2];
    bfrag Bx[4];
    facc  bsp[4];
    float sw4[4];
#pragma unroll
    for (int q = 0; q < 4; ++q) {
        const int n = q * H_ + hcol;
#pragma unroll
        for (int ks = 0; ks < 2; ++ks)
            B8[q][ks] = *(const v4i*)(w8 + n * 128 + ks * 64 + lk * 16);
        Bx[q] = *(const bfrag*)(wih_bf + n * 32 + lk * 8);
        const float b = bias[n];
        bsp[q] = (facc){b, b, b, b};
        sw4[q] = sw[n];
    }
#pragma unroll
    for (int q = 0; q < 4; ++q) {          // pin: forbid in-loop remat
        asm volatile("" : "+v"(B8[q][0]));
        asm volatile("" : "+v"(B8[q][1]));
        asm volatile("" : "+v"(Bx[q]));
        asm volatile("" : "+v"(bsp[q]));
    }

    // swizzled LDS offsets
    const int swzk = (lr & 7) << 4;
    const int hoff0 = (lr * 128 + lk * 16) ^ swzk;
    const int hoff1 = (lr * 128 + 64 + lk * 16) ^ swzk;
    const int xoff  = (lr * 64 + lk * 16) ^ swzk;
    const int stoff = (lk * 128 + hcol) ^ ((lk & 7) << 4);
    const int lrsrc = lr;
    const bool b0 = (lk & 1) != 0;
    const bool b1 = (lk & 2) != 0;

    // staging: thread -> (tl 0..63, seq 0..3, k-half) for both groups
    const int skb = tid & 1, sseq = (tid >> 1) & 3, stl = tid >> 3;
    const int seqA = m0 + sseq, seqB = m0 + 4 + sseq;
    const int bbA = seqA / N_, nnA = seqA % N_;
    const int bbB = seqB / N_, nnB = seqB % N_;
    const float* xA = x + (((size_t)bbA * T_ + stl) * N_ + nnA) * F_ + skb * 8;
    const float* xB = x + (((size_t)bbB * T_ + stl) * N_ + nnB) * F_ + skb * 8;
    const int sbyte = (stl * 256 + sseq * 64 + skb * 16) ^ ((sseq & 7) << 4);

    // ---- init: zero LDS (x pad + h rows stay 0), prefetch chunk 0 ----
    for (int i = tid; i < LDSZ / 4; i += 512) ((int*)lds)[i] = 0;
    float4 pA0 = *(const float4*)xA, pA1 = *(const float4*)(xA + 4);
    float4 pB0 = *(const float4*)xB, pB1 = *(const float4*)(xB + 4);
    bar();

    float ccA = 0.0f, ccB = 0.0f;
    v4i  accA[4], accB[4];
    facc xaccA[4], xaccB[4];
#pragma unroll
    for (int q = 0; q < 4; ++q) {           // epilogue_B(-1) must write h=0
        accB[q] = (v4i){0, 0, 0, 0};
        xaccB[q] = (facc){0.f, 0.f, 0.f, 0.f};
    }

#pragma unroll 1
    for (int chunk = 0; chunk < T_ / TCH; ++chunk) {
        // stage prefetched x chunk (both groups)
        {
            uint4 oa, ob;
            oa.x = cvt_pk_bf16(pA0.x, pA0.y); oa.y = cvt_pk_bf16(pA0.z, pA0.w);
            oa.z = cvt_pk_bf16(pA1.x, pA1.y); oa.w = cvt_pk_bf16(pA1.z, pA1.w);
            ob.x = cvt_pk_bf16(pB0.x, pB0.y); ob.y = cvt_pk_bf16(pB0.z, pB0.w);
            ob.z = cvt_pk_bf16(pB1.x, pB1.y); ob.w = cvt_pk_bf16(pB1.z, pB1.w);
            *(uint4*)(lds + SXA + sbyte) = oa;
            *(uint4*)(lds + SXB + sbyte) = ob;
        }
        if (chunk + 1 < T_ / TCH) {          // prefetch next chunk (in flight
            xA += TCH * N_ * F_;             //  across the whole inner loop)
            xB += TCH * N_ * F_;
            pA0 = *(const float4*)xA; pA1 = *(const float4*)(xA + 4);
            pB0 = *(const float4*)xB; pB1 = *(const float4*)(xB + 4);
        }
        bar();

#pragma unroll 1
        for (int tl = 0; tl < TCH; ++tl) {
            // half A: compute A(t) from SHA/SXA; finish B(t-1) -> write SHB
            half_step(lds, SHA, SHB, SXA + tl * 256 + xoff,
                      B8, Bx, bsp, sw4, accA, xaccA, accB, xaccB, ccB,
                      hoff0, hoff1, stoff, lrsrc, b0, b1);
            bar();
            // half B: compute B(t) from SHB/SXB; finish A(t) -> write SHA
            half_step(lds, SHB, SHA, SXB + tl * 256 + xoff,
                      B8, Bx, bsp, sw4, accB, xaccB, accA, xaccA, ccA,
                      hoff0, hoff1, stoff, lrsrc, b0, b1);
            bar();
        }
    }

    // drain: epilogue B(511) -> write SHB
    epi_spread(lds, SHB, accB, xaccB, sw4, ccB, stoff, lrsrc, b0, b1);
    bar();

    // readout: h8 -> bf16 (8 seqs x 128 cols, 2 elements/thread)
    for (int e = tid; e < MBLK * H_; e += 512) {
        const int g = e >> 9, s = (e >> 7) & 3, c = e & 127;
        const int byte = (s * 128 + c) ^ ((s & 7) << 4);
        const signed char v = *(const signed char*)(lds + (g ? SHB : SHA) + byte);
        h_out[(size_t)(m0 + g * 4 + s) * H_ + c] = f2bf((float)v * (1.0f / 127.0f));
    }
}

// ---------------------------------------------------------------------------
// Head kernel: one block per batch element b. GCN + linears + sigmoid.
// ---------------------------------------------------------------------------
__global__ __launch_bounds__(256) void head_kernel(
    const float* __restrict__ adj,
    const float* __restrict__ W_gcn, const float* __restrict__ b_gcn,
    const float* __restrict__ W_out, const float* __restrict__ b_out,
    const float* __restrict__ W_lin1, const float* __restrict__ b_lin1,
    const unsigned short* __restrict__ h_in,   // [896][128] bf16
    float* __restrict__ out)                   // [B, 28]
{
    const int b   = blockIdx.x;
    const int tid = threadIdx.x;

    __shared__ float s_A[N_][N_];
    __shared__ float s_d[N_];
    __shared__ float s_h[N_][H_];
    __shared__ float s_xg[N_][H_];
    __shared__ float s_g1[N_][64];
    __shared__ float s_s[N_];

    for (int idx = tid; idx < N_ * H_; idx += 256)
        s_h[idx >> 7][idx & 127] = bf2f(h_in[(size_t)b * N_ * H_ + idx]);

    if (tid < N_) {
        float sum = 0.0f;
        for (int j = 0; j < N_; ++j)
            sum += adj[tid * N_ + j] + (tid == j ? 1.0f : 0.0f);
        s_d[tid] = rsqrtf(sum);
    }
    __syncthreads();

    if (tid < N_ * N_) {
        const int i = tid / N_, j = tid % N_;
        const float a = adj[i * N_ + j] + (i == j ? 1.0f : 0.0f);
        s_A[i][j] = s_d[i] * a * s_d[j];
    }
    __syncthreads();

    for (int idx = tid; idx < N_ * H_; idx += 256) {
        const int i = idx >> 7, k = idx & 127;
        float acc = 0.0f;
#pragma unroll
        for (int j = 0; j < N_; ++j) acc += s_A[i][j] * s_h[j][k];
        s_xg[i][k] = acc;
    }
    __syncthreads();

    for (int idx = tid; idx < N_ * 64; idx += 256) {
        const int i = idx >> 6, q = idx & 63;
        float a0 = 0.f, a1 = 0.f, a2 = 0.f, a3 = 0.f;
#pragma unroll
        for (int k = 0; k < H_; k += 4) {
            a0 += s_xg[i][k+0] * W_gcn[q * H_ + k+0];
            a1 += s_xg[i][k+1] * W_gcn[q * H_ + k+1];
            a2 += s_xg[i][k+2] * W_gcn[q * H_ + k+2];
            a3 += s_xg[i][k+3] * W_gcn[q * H_ + k+3];
        }
        const float acc = b_gcn[q] + ((a0 + a1) + (a2 + a3));
        s_g1[i][q] = fmaxf(acc, 0.0f);
    }
    __syncthreads();

    if (tid < N_) {
        float acc = b_out[0];
#pragma unroll
        for (int q = 0; q < 64; ++q) acc += s_g1[tid][q] * W_out[q];
        s_s[tid] = acc;
    }
    __syncthreads();

    if (tid < 28) {
        float acc = b_lin1[tid];
#pragma unroll
        for (int i = 0; i < N_; ++i) acc += s_s[i] * W_lin1[tid * N_ + i];
        out[b * 28 + tid] = 1.0f / (1.0f + __expf(-acc));
    }
}

extern "C" void kernel_launch(void* const* d_in, const int* in_sizes, int n_in,
                              void* d_out, int out_size, void* d_ws, size_t ws_size,
                              hipStream_t stream) {
    const float* x      = (const float*)d_in[0];
    const float* adj    = (const float*)d_in[1];
    const float* W_ih   = (const float*)d_in[2];
    const float* W_hh   = (const float*)d_in[3];
    const float* b_ih   = (const float*)d_in[4];
    const float* b_hh   = (const float*)d_in[5];
    const float* W_gcn  = (const float*)d_in[6];
    const float* b_gcn  = (const float*)d_in[7];
    const float* W_out  = (const float*)d_in[8];
    const float* b_out  = (const float*)d_in[9];
    const float* W_lin1 = (const float*)d_in[10];
    const float* b_lin1 = (const float*)d_in[11];
    float* out = (float*)d_out;

    // workspace layout (bytes): total 333824
    char* ws = (char*)d_ws;
    signed char*    w8     = (signed char*)(ws);              // 512*128   =  65536
    short*          wih_bf = (short*)(ws + 65536);            // 512*32*2  =  32768
    float*          bias   = (float*)(ws + 98304);            // 512*4     =   2048
    float*          sw     = (float*)(ws + 100352);           // 512*4     =   2048
    float*          inv127 = (float*)(ws + 102400);           // 512*4     =   2048
    unsigned short* h_last = (unsigned short*)(ws + 104448);  // 896*128*2 = 229376

    prep1_kernel<<<1, 512, 0, stream>>>(W_hh, b_ih, b_hh, inv127, sw, bias);
    prep2_kernel<<<128, 512, 0, stream>>>(W_hh, W_ih, inv127, w8, wih_bf);
    lstm_kernel<<<NBLK, 512, 0, stream>>>(x, w8, wih_bf, bias, sw, h_last);
    head_kernel<<<B_, 256, 0, stream>>>(adj, W_gcn, b_gcn, W_out, b_out,
                                        W_lin1, b_lin1, h_last, out);
}

// Round 8
// 659.704 us; speedup vs baseline: 1.7221x; 1.1524x over previous
//
#include <hip/hip_runtime.h>
#include <hip/hip_bf16.h>

#define B_   64
#define T_   512
#define N_   14
#define F_   16
#define H_   128
#define G4_  512
#define TCH  64     // timesteps staged per LDS chunk
#define MBLK 4      // sequences per block (2 groups of 2)
#define NBLK 224

typedef __attribute__((ext_vector_type(8))) short bfrag;  // 8 bf16
typedef __attribute__((ext_vector_type(4))) float facc;   // fp32 acc
typedef __attribute__((ext_vector_type(4))) int   v4i;    // i8x16 / i32x4

#define L2E   1.4426950408889634f
#define L2E2  2.8853900817779268f

// LDS byte offsets
#define SXA 0        // x group A: [64 tl][2 seq][32 k] bf16 (k>=16 zero) = 8 KB
#define SXB 8192
#define SH0 16384    // h bufs: [group(2)][parity(2)][2 rows][128] i8 = 1 KB
#define LDSZ 17408

__device__ __forceinline__ short f2bf(float f) {
    unsigned u = __builtin_bit_cast(unsigned, f);
    return (short)((u + 0x7FFFu + ((u >> 16) & 1u)) >> 16);
}
__device__ __forceinline__ float bf2f(unsigned short s) {
    return __builtin_bit_cast(float, (unsigned)s << 16);
}
__device__ __forceinline__ unsigned cvt_pk_bf16(float a, float b) {
    unsigned r;
    asm("v_cvt_pk_bf16_f32 %0, %1, %2" : "=v"(r) : "v"(a), "v"(b));
    return r;
}
// i8 MFMA (validated rounds 6-7)
__device__ __forceinline__ v4i mfma_i8(v4i a, v4i b, v4i c) {
    v4i d;
    asm("v_mfma_i32_16x16x64_i8 %0, %1, %2, %3"
        : "=&v"(d) : "v"(a), "v"(b), "v"(c));
    return d;
}
// lgkm-only barrier: global prefetch loads stay in flight across barriers.
__device__ __forceinline__ void bar() {
    asm volatile("s_waitcnt lgkmcnt(0)" ::: "memory");
    __builtin_amdgcn_s_barrier();
    asm volatile("" ::: "memory");
}

// ---------------------------------------------------------------------------
// prep1: per-gate-row max of W_hh -> i8 scale; fused biases; log2e pre-scale
// (2x for the g-gate section) so the epilogue uses native exp2.
// ---------------------------------------------------------------------------
__global__ void prep1_kernel(const float* __restrict__ W_hh,
                             const float* __restrict__ b_ih, const float* __restrict__ b_hh,
                             float* __restrict__ inv127, float* __restrict__ sw,
                             float* __restrict__ bias) {
    const int g = threadIdx.x;            // 0..511
    float mx = 0.0f;
    for (int k = 0; k < H_; ++k) mx = fmaxf(mx, fabsf(W_hh[g * H_ + k]));
    const float sc = (g >= 256 && g < 384) ? L2E2 : L2E;
    inv127[g] = 127.0f / mx;
    sw[g]     = mx * sc * (1.0f / 16129.0f);   // mx/127 * 1/127 * log2e-scale
    bias[g]   = (b_ih[g] + b_hh[g]) * sc;
}

// ---------------------------------------------------------------------------
// prep2: W_hh -> i8 (row-scaled); W_ih -> bf16 (log2e-scaled, K padded 16->32)
// ---------------------------------------------------------------------------
__global__ void prep2_kernel(const float* __restrict__ W_hh, const float* __restrict__ W_ih,
                             const float* __restrict__ inv127,
                             signed char* __restrict__ w8, short* __restrict__ wih_bf) {
    const int i = blockIdx.x * blockDim.x + threadIdx.x;   // 0..65535
    if (i < G4_ * H_)
        w8[i] = (signed char)(int)rintf(W_hh[i] * inv127[i >> 7]);
    if (i < G4_ * 32) {
        const int n = i >> 5, k = i & 31;
        const float sc = (n >= 256 && n < 384) ? L2E2 : L2E;
        wih_bf[i] = (k < F_) ? f2bf(W_ih[n * F_ + k] * sc) : (short)0;
    }
}

// ---------------------------------------------------------------------------
// Epilogue for one group: regs 0/1 of acc hold seq0/seq1 gates on EVERY lane
// (broadcast-row duplication). 2 gate chains/lane; lanes lk==0 write h8.
// ---------------------------------------------------------------------------
__device__ __forceinline__ void epi2(char* hw,
    const v4i (&acc)[4], const facc (&xacc)[4], const float (&sw4)[4],
    float& cc0, float& cc1, int hcol, bool writer)
{
#pragma unroll
    for (int r = 0; r < 2; ++r) {
        const float z0 = (float)acc[0][r] * sw4[0] + xacc[0][r];
        const float z1 = (float)acc[1][r] * sw4[1] + xacc[1][r];
        const float z2 = (float)acc[2][r] * sw4[2] + xacc[2][r];
        const float z3 = (float)acc[3][r] * sw4[3] + xacc[3][r];
        const float ea = exp2f(-z0);
        const float ef = exp2f(-z1);
        const float eo = exp2f(-z3);
        const float eg = exp2f(-fabsf(z2));
        const float d1 = (1.0f + ea) * (1.0f + eg);
        const float d2 = 1.0f + ef;
        const float rP = __builtin_amdgcn_rcpf(d1 * d2);   // shared rcp
        const float ig = __builtin_copysignf((1.0f - eg) * (rP * d2), z2);
        float& cc = r ? cc1 : cc0;
        cc = (rP * d1) * cc + ig;
        const float ec = exp2f(-L2E2 * fabsf(cc));
        const float hv = __builtin_copysignf(
            (1.0f - ec) * __builtin_amdgcn_rcpf((1.0f + eo) * (1.0f + ec)), cc);
        if (writer) {
            const int addr = r * 128 + (hcol ^ (r << 4));
            *(signed char*)(hw + addr) = (signed char)(int)rintf(hv * 127.0f);
        }
    }
}

// ---------------------------------------------------------------------------
// One synchronous step for BOTH groups; single barrier. P = parity (read
// h[P], write h[P^1]). PREF: compute next step's xacc (reads SX only).
// ---------------------------------------------------------------------------
template<int P, bool PREF>
__device__ __forceinline__ void lstm_step(char* lds, int tl,
    const v4i (&B8)[4][2], const bfrag (&Bx)[4], const facc (&bsp)[4],
    const float (&sw4)[4],
    facc (&xaccA)[4], facc (&xaccB)[4], float (&cc)[4],
    int hrd, int xrd, int hcol, bool writer)
{
    bar();
    const char* HA_R = lds + SH0 + P * 256;
    const char* HB_R = lds + SH0 + 512 + P * 256;
    char* HA_W = lds + SH0 + (P ^ 1) * 256;
    char* HB_W = lds + SH0 + 512 + (P ^ 1) * 256;

    const v4i aA0 = *(const v4i*)(HA_R + hrd);
    const v4i aA1 = *(const v4i*)(HA_R + hrd + 64);
    const v4i aB0 = *(const v4i*)(HB_R + hrd);
    const v4i aB1 = *(const v4i*)(HB_R + hrd + 64);

    const v4i z4 = (v4i){0, 0, 0, 0};
    v4i accA[4], accB[4];
#pragma unroll
    for (int q = 0; q < 4; ++q) accA[q] = mfma_i8(aA0, B8[q][0], z4);
#pragma unroll
    for (int q = 0; q < 4; ++q) accB[q] = mfma_i8(aB0, B8[q][0], z4);
#pragma unroll
    for (int q = 0; q < 4; ++q) accA[q] = mfma_i8(aA1, B8[q][1], accA[q]);
#pragma unroll
    for (int q = 0; q < 4; ++q) accB[q] = mfma_i8(aB1, B8[q][1], accB[q]);

    epi2(HA_W, accA, xaccA, sw4, cc[0], cc[1], hcol, writer);
    epi2(HB_W, accB, xaccB, sw4, cc[2], cc[3], hcol, writer);

    if (PREF) {   // next step's x-contribution (SX-only; off the h-chain)
        const bfrag axA = *(const bfrag*)(lds + SXA + (tl + 1) * 128 + xrd);
        const bfrag axB = *(const bfrag*)(lds + SXB + (tl + 1) * 128 + xrd);
#pragma unroll
        for (int q = 0; q < 4; ++q)
            xaccA[q] = __builtin_amdgcn_mfma_f32_16x16x32_bf16(axA, Bx[q], bsp[q], 0, 0, 0);
#pragma unroll
        for (int q = 0; q < 4; ++q)
            xaccB[q] = __builtin_amdgcn_mfma_f32_16x16x32_bf16(axB, Bx[q], bsp[q], 0, 0, 0);
    }
}

// ---------------------------------------------------------------------------
// LSTM: 224 blocks x 512 thr; block owns 4 seqs as 2 synchronous groups of 2.
// Wave w owns h-cols [16w,16w+16) across all 4 gate sections.
// ---------------------------------------------------------------------------
__global__ __launch_bounds__(512, 2) void lstm_kernel(
    const float* __restrict__ x,            // [B, T, N, F] fp32
    const signed char* __restrict__ w8,     // [512][128] i8
    const short* __restrict__ wih_bf,       // [512][32] bf16
    const float* __restrict__ bias,         // [512] (log2e-scaled)
    const float* __restrict__ sw,           // [512] descale * log2e
    unsigned short* __restrict__ h_out)     // [896][128] bf16
{
    const int m0  = blockIdx.x * MBLK;
    const int tid = threadIdx.x;
    const int w   = tid >> 6, l = tid & 63;
    const int lr  = l & 15, lk = l >> 4;
    const int hcol = w * 16 + lr;

    __shared__ __align__(16) char lds[LDSZ];

    // ---- loop-invariant register state ----
    v4i   B8[4][2];
    bfrag Bx[4];
    facc  bsp[4];
    float sw4[4];
#pragma unroll
    for (int q = 0; q < 4; ++q) {
        const int n = q * H_ + hcol;
#pragma unroll
        for (int ks = 0; ks < 2; ++ks)
            B8[q][ks] = *(const v4i*)(w8 + n * 128 + ks * 64 + lk * 16);
        Bx[q] = *(const bfrag*)(wih_bf + n * 32 + lk * 8);
        const float b = bias[n];
        bsp[q] = (facc){b, b, b, b};
        sw4[q] = sw[n];
    }
#pragma unroll
    for (int q = 0; q < 4; ++q) {          // pin: forbid in-loop remat
        asm volatile("" : "+v"(B8[q][0]));
        asm volatile("" : "+v"(B8[q][1]));
        asm volatile("" : "+v"(Bx[q]));
        asm volatile("" : "+v"(bsp[q]));
    }

    // lane offsets (broadcast rows: row index = lr&1 duplicates across lanes)
    const int r2  = lr & 1;
    const int hrd = r2 * 128 + ((lk * 16) ^ (r2 << 4));
    const int xrd = r2 * 64 + lk * 16;
    const bool writer = (lk == 0);

    // staging: thread -> (group, tl, seq, k-half); 512 slots = 512 threads
    const int sg  = tid >> 8;              // 0 = A, 1 = B
    const int ss  = tid & 255;
    const int stl = ss >> 2, sseq = (ss >> 1) & 1, skb = ss & 1;
    const int seqg = m0 + sg * 2 + sseq;
    const int bb = seqg / N_, nn = seqg % N_;
    const float* xq = x + (((size_t)bb * T_ + stl) * N_ + nn) * F_ + skb * 8;
    const int sbyte = (sg ? SXB : SXA) + stl * 128 + sseq * 64 + skb * 16;

    // ---- init: zero LDS (x pad stays 0; h[parity 0] = initial state 0) ----
    for (int i = tid; i < LDSZ / 4; i += 512) ((int*)lds)[i] = 0;
    float4 p0 = *(const float4*)xq, p1 = *(const float4*)(xq + 4);

    float cc[4] = {0.f, 0.f, 0.f, 0.f};
    facc  xaccA[4], xaccB[4];
    bar();

#pragma unroll 1
    for (int chunk = 0; chunk < T_ / TCH; ++chunk) {
        // stage prefetched x chunk
        {
            uint4 o;
            o.x = cvt_pk_bf16(p0.x, p0.y); o.y = cvt_pk_bf16(p0.z, p0.w);
            o.z = cvt_pk_bf16(p1.x, p1.y); o.w = cvt_pk_bf16(p1.z, p1.w);
            *(uint4*)(lds + sbyte) = o;
        }
        if (chunk + 1 < T_ / TCH) {        // next chunk loads stay in flight
            xq += TCH * N_ * F_;
            p0 = *(const float4*)xq; p1 = *(const float4*)(xq + 4);
        }
        bar();

        // preamble: xacc for tl=0
        {
            const bfrag axA = *(const bfrag*)(lds + SXA + xrd);
            const bfrag axB = *(const bfrag*)(lds + SXB + xrd);
#pragma unroll
            for (int q = 0; q < 4; ++q)
                xaccA[q] = __builtin_amdgcn_mfma_f32_16x16x32_bf16(axA, Bx[q], bsp[q], 0, 0, 0);
#pragma unroll
            for (int q = 0; q < 4; ++q)
                xaccB[q] = __builtin_amdgcn_mfma_f32_16x16x32_bf16(axB, Bx[q], bsp[q], 0, 0, 0);
        }

#pragma unroll 1
        for (int tl = 0; tl < TCH; tl += 2) {
            lstm_step<0, true>(lds, tl, B8, Bx, bsp, sw4, xaccA, xaccB, cc,
                               hrd, xrd, hcol, writer);
            if (tl + 2 < TCH)
                lstm_step<1, true>(lds, tl + 1, B8, Bx, bsp, sw4, xaccA, xaccB, cc,
                                   hrd, xrd, hcol, writer);
            else
                lstm_step<1, false>(lds, tl + 1, B8, Bx, bsp, sw4, xaccA, xaccB, cc,
                                    hrd, xrd, hcol, writer);
        }
    }
    bar();   // final h writes (parity 0 bufs) -> readout

    // readout: h8 -> bf16 (4 seqs x 128 cols; 1 elem/thread)
    {
        const int g = tid >> 8, s = (tid >> 7) & 1, c = tid & 127;
        const int addr = SH0 + g * 512 + s * 128 + (c ^ (s << 4));
        const signed char v = *(const signed char*)(lds + addr);
        h_out[(size_t)(m0 + g * 2 + s) * H_ + c] = f2bf((float)v * (1.0f / 127.0f));
    }
}

// ---------------------------------------------------------------------------
// Head kernel: one block per batch element b. GCN + linears + sigmoid.
// ---------------------------------------------------------------------------
__global__ __launch_bounds__(256) void head_kernel(
    const float* __restrict__ adj,
    const float* __restrict__ W_gcn, const float* __restrict__ b_gcn,
    const float* __restrict__ W_out, const float* __restrict__ b_out,
    const float* __restrict__ W_lin1, const float* __restrict__ b_lin1,
    const unsigned short* __restrict__ h_in,   // [896][128] bf16
    float* __restrict__ out)                   // [B, 28]
{
    const int b   = blockIdx.x;
    const int tid = threadIdx.x;

    __shared__ float s_A[N_][N_];
    __shared__ float s_d[N_];
    __shared__ float s_h[N_][H_];
    __shared__ float s_xg[N_][H_];
    __shared__ float s_g1[N_][64];
    __shared__ float s_s[N_];

    for (int idx = tid; idx < N_ * H_; idx += 256)
        s_h[idx >> 7][idx & 127] = bf2f(h_in[(size_t)b * N_ * H_ + idx]);

    if (tid < N_) {
        float sum = 0.0f;
        for (int j = 0; j < N_; ++j)
            sum += adj[tid * N_ + j] + (tid == j ? 1.0f : 0.0f);
        s_d[tid] = rsqrtf(sum);
    }
    __syncthreads();

    if (tid < N_ * N_) {
        const int i = tid / N_, j = tid % N_;
        const float a = adj[i * N_ + j] + (i == j ? 1.0f : 0.0f);
        s_A[i][j] = s_d[i] * a * s_d[j];
    }
    __syncthreads();

    for (int idx = tid; idx < N_ * H_; idx += 256) {
        const int i = idx >> 7, k = idx & 127;
        float acc = 0.0f;
#pragma unroll
        for (int j = 0; j < N_; ++j) acc += s_A[i][j] * s_h[j][k];
        s_xg[i][k] = acc;
    }
    __syncthreads();

    for (int idx = tid; idx < N_ * 64; idx += 256) {
        const int i = idx >> 6, q = idx & 63;
        float a0 = 0.f, a1 = 0.f, a2 = 0.f, a3 = 0.f;
#pragma unroll
        for (int k = 0; k < H_; k += 4) {
            a0 += s_xg[i][k+0] * W_gcn[q * H_ + k+0];
            a1 += s_xg[i][k+1] * W_gcn[q * H_ + k+1];
            a2 += s_xg[i][k+2] * W_gcn[q * H_ + k+2];
            a3 += s_xg[i][k+3] * W_gcn[q * H_ + k+3];
        }
        const float acc = b_gcn[q] + ((a0 + a1) + (a2 + a3));
        s_g1[i][q] = fmaxf(acc, 0.0f);
    }
    __syncthreads();

    if (tid < N_) {
        float acc = b_out[0];
#pragma unroll
        for (int q = 0; q < 64; ++q) acc += s_g1[tid][q] * W_out[q];
        s_s[tid] = acc;
    }
    __syncthreads();

    if (tid < 28) {
        float acc = b_lin1[tid];
#pragma unroll
        for (int i = 0; i < N_; ++i) acc += s_s[i] * W_lin1[tid * N_ + i];
        out[b * 28 + tid] = 1.0f / (1.0f + __expf(-acc));
    }
}

extern "C" void kernel_launch(void* const* d_in, const int* in_sizes, int n_in,
                              void* d_out, int out_size, void* d_ws, size_t ws_size,
                              hipStream_t stream) {
    const float* x      = (const float*)d_in[0];
    const float* adj    = (const float*)d_in[1];
    const float* W_ih   = (const float*)d_in[2];
    const float* W_hh   = (const float*)d_in[3];
    const float* b_ih   = (const float*)d_in[4];
    const float* b_hh   = (const float*)d_in[5];
    const float* W_gcn  = (const float*)d_in[6];
    const float* b_gcn  = (const float*)d_in[7];
    const float* W_out  = (const float*)d_in[8];
    const float* b_out  = (const float*)d_in[9];
    const float* W_lin1 = (const float*)d_in[10];
    const float* b_lin1 = (const float*)d_in[11];
    float* out = (float*)d_out;

    // workspace layout (bytes): total 333824
    char* ws = (char*)d_ws;
    signed char*    w8     = (signed char*)(ws);              // 512*128   =  65536
    short*          wih_bf = (short*)(ws + 65536);            // 512*32*2  =  32768
    float*          bias   = (float*)(ws + 98304);            // 512*4     =   2048
    float*          sw     = (float*)(ws + 100352);           // 512*4     =   2048
    float*          inv127 = (float*)(ws + 102400);           // 512*4     =   2048
    unsigned short* h_last = (unsigned short*)(ws + 104448);  // 896*128*2 = 229376

    prep1_kernel<<<1, 512, 0, stream>>>(W_hh, b_ih, b_hh, inv127, sw, bias);
    prep2_kernel<<<128, 512, 0, stream>>>(W_hh, W_ih, inv127, w8, wih_bf);
    lstm_kernel<<<NBLK, 512, 0, stream>>>(x, w8, wih_bf, bias, sw, h_last);
    head_kernel<<<B_, 256, 0, stream>>>(adj, W_gcn, b_gcn, W_out, b_out,
                                        W_lin1, b_lin1, h_last, out);
}

// Round 9
// 383.297 us; speedup vs baseline: 2.9639x; 1.7211x over previous
//
#include <hip/hip_runtime.h>
#include <hip/hip_bf16.h>

#define B_   64
#define T_   512
#define N_   14
#define F_   16
#define H_   128
#define G4_  512
#define TCH  64     // timesteps staged per LDS chunk
#define MBLK 4      // sequences per block (2 groups of 2)
#define NBLK 224

typedef __attribute__((ext_vector_type(8))) short bfrag;  // 8 bf16
typedef __attribute__((ext_vector_type(4))) float facc;   // fp32 acc
typedef __attribute__((ext_vector_type(4))) int   v4i;    // i8x16 / i32x4

#define L2E   1.4426950408889634f
#define L2E2  2.8853900817779268f

// LDS byte offsets
#define SXA 0        // x group A: [64 tl][2 seq][32 k] bf16 (k>=16 zero) = 8 KB
#define SXB 8192
#define SH0 16384    // h bufs: [group(2)][parity(2)][2 rows][128] i8 = 1 KB
#define LDSZ 17408

__device__ __forceinline__ short f2bf(float f) {
    unsigned u = __builtin_bit_cast(unsigned, f);
    return (short)((u + 0x7FFFu + ((u >> 16) & 1u)) >> 16);
}
__device__ __forceinline__ float bf2f(unsigned short s) {
    return __builtin_bit_cast(float, (unsigned)s << 16);
}
__device__ __forceinline__ unsigned cvt_pk_bf16(float a, float b) {
    unsigned r;
    asm("v_cvt_pk_bf16_f32 %0, %1, %2" : "=v"(r) : "v"(a), "v"(b));
    return r;
}
// i8 MFMA (validated rounds 6-8)
__device__ __forceinline__ v4i mfma_i8(v4i a, v4i b, v4i c) {
    v4i d;
    asm("v_mfma_i32_16x16x64_i8 %0, %1, %2, %3"
        : "=&v"(d) : "v"(a), "v"(b), "v"(c));
    return d;
}
// lgkm-only barrier: global prefetch loads stay in flight across barriers.
__device__ __forceinline__ void bar() {
    asm volatile("s_waitcnt lgkmcnt(0)" ::: "memory");
    __builtin_amdgcn_s_barrier();
    asm volatile("" ::: "memory");
}

// ---------------------------------------------------------------------------
// prep1: per-gate-row max of W_hh -> i8 scale; fused biases; log2e pre-scale
// (2x for the g-gate section) so the epilogue uses native exp2.
// ---------------------------------------------------------------------------
__global__ void prep1_kernel(const float* __restrict__ W_hh,
                             const float* __restrict__ b_ih, const float* __restrict__ b_hh,
                             float* __restrict__ inv127, float* __restrict__ sw,
                             float* __restrict__ bias) {
    const int g = threadIdx.x;            // 0..511
    float mx = 0.0f;
    for (int k = 0; k < H_; ++k) mx = fmaxf(mx, fabsf(W_hh[g * H_ + k]));
    const float sc = (g >= 256 && g < 384) ? L2E2 : L2E;
    inv127[g] = 127.0f / mx;
    sw[g]     = mx * sc * (1.0f / 16129.0f);   // mx/127 * 1/127 * log2e-scale
    bias[g]   = (b_ih[g] + b_hh[g]) * sc;
}

// ---------------------------------------------------------------------------
// prep2: W_hh -> i8 (row-scaled); W_ih -> bf16 (log2e-scaled, K padded 16->32)
// ---------------------------------------------------------------------------
__global__ void prep2_kernel(const float* __restrict__ W_hh, const float* __restrict__ W_ih,
                             const float* __restrict__ inv127,
                             signed char* __restrict__ w8, short* __restrict__ wih_bf) {
    const int i = blockIdx.x * blockDim.x + threadIdx.x;   // 0..65535
    if (i < G4_ * H_)
        w8[i] = (signed char)(int)rintf(W_hh[i] * inv127[i >> 7]);
    if (i < G4_ * 32) {
        const int n = i >> 5, k = i & 31;
        const float sc = (n >= 256 && n < 384) ? L2E2 : L2E;
        wih_bf[i] = (k < F_) ? f2bf(W_ih[n * F_ + k] * sc) : (short)0;
    }
}

// ---------------------------------------------------------------------------
// One synchronous step for BOTH groups; single barrier. P = parity (read
// h[P], write h[P^1]). PREF: compute next step's xacc (reads SX only).
// Epilogue is lane-deduplicated: lane (lk,lr) owns the single chain
// (g,s,col) = (lk>>1, lk&1, hcol); selects its z from regs via cndmask.
// ---------------------------------------------------------------------------
template<int P, bool PREF>
__device__ __forceinline__ void lstm_step(char* lds, int tl,
    const v4i (&B8)[4][2], const bfrag (&Bx)[4], const facc (&bsp)[4],
    const float (&sw4)[4],
    facc (&xaccA)[4], facc (&xaccB)[4], float& cc,
    int hrd, int xrd, int wbase, bool b0, bool b1)
{
    bar();
    const char* HA_R = lds + SH0 + P * 256;
    const char* HB_R = lds + SH0 + 512 + P * 256;

    const v4i aA0 = *(const v4i*)(HA_R + hrd);
    const v4i aA1 = *(const v4i*)(HA_R + hrd + 64);
    const v4i aB0 = *(const v4i*)(HB_R + hrd);
    const v4i aB1 = *(const v4i*)(HB_R + hrd + 64);

    const v4i z4 = (v4i){0, 0, 0, 0};
    v4i accA[4], accB[4];
#pragma unroll
    for (int q = 0; q < 4; ++q) accA[q] = mfma_i8(aA0, B8[q][0], z4);
#pragma unroll
    for (int q = 0; q < 4; ++q) accB[q] = mfma_i8(aB0, B8[q][0], z4);
#pragma unroll
    for (int q = 0; q < 4; ++q) accA[q] = mfma_i8(aA1, B8[q][1], accA[q]);
#pragma unroll
    for (int q = 0; q < 4; ++q) accB[q] = mfma_i8(aB1, B8[q][1], accB[q]);

    // ---- lane-select: one (g,s) chain per lane; static reg indices only ----
    float z[4];
#pragma unroll
    for (int q = 0; q < 4; ++q) {
        const int   iA = b0 ? accA[q][1] : accA[q][0];
        const int   iB = b0 ? accB[q][1] : accB[q][0];
        const int   iz = b1 ? iB : iA;
        const float xA = b0 ? xaccA[q][1] : xaccA[q][0];
        const float xB = b0 ? xaccB[q][1] : xaccB[q][0];
        const float xz = b1 ? xB : xA;
        z[q] = (float)iz * sw4[q] + xz;
    }

    // ---- single gate chain ----
    const float ea = exp2f(-z[0]);
    const float ef = exp2f(-z[1]);
    const float eo = exp2f(-z[3]);
    const float eg = exp2f(-fabsf(z[2]));
    const float d1 = (1.0f + ea) * (1.0f + eg);
    const float d2 = 1.0f + ef;
    const float rP = __builtin_amdgcn_rcpf(d1 * d2);       // shared rcp
    const float ig = __builtin_copysignf((1.0f - eg) * (rP * d2), z[2]);
    cc = (rP * d1) * cc + ig;
    const float ec = exp2f(-L2E2 * fabsf(cc));
    const float hv = __builtin_copysignf(
        (1.0f - ec) * __builtin_amdgcn_rcpf((1.0f + eo) * (1.0f + ec)), cc);
    *(signed char*)(lds + wbase + (P ^ 1) * 256) =
        (signed char)(int)rintf(hv * 127.0f);

    if (PREF) {   // next step's x-contribution (SX-only; off the h-chain)
        const bfrag axA = *(const bfrag*)(lds + SXA + (tl + 1) * 128 + xrd);
        const bfrag axB = *(const bfrag*)(lds + SXB + (tl + 1) * 128 + xrd);
#pragma unroll
        for (int q = 0; q < 4; ++q)
            xaccA[q] = __builtin_amdgcn_mfma_f32_16x16x32_bf16(axA, Bx[q], bsp[q], 0, 0, 0);
#pragma unroll
        for (int q = 0; q < 4; ++q)
            xaccB[q] = __builtin_amdgcn_mfma_f32_16x16x32_bf16(axB, Bx[q], bsp[q], 0, 0, 0);
    }
}

// ---------------------------------------------------------------------------
// LSTM: 224 blocks x 512 thr; block owns 4 seqs as 2 synchronous groups of 2.
// Wave w owns h-cols [16w,16w+16) across all 4 gate sections.
// ---------------------------------------------------------------------------
__global__ __launch_bounds__(512, 2) void lstm_kernel(
    const float* __restrict__ x,            // [B, T, N, F] fp32
    const signed char* __restrict__ w8,     // [512][128] i8
    const short* __restrict__ wih_bf,       // [512][32] bf16
    const float* __restrict__ bias,         // [512] (log2e-scaled)
    const float* __restrict__ sw,           // [512] descale * log2e
    unsigned short* __restrict__ h_out)     // [896][128] bf16
{
    const int m0  = blockIdx.x * MBLK;
    const int tid = threadIdx.x;
    const int w   = tid >> 6, l = tid & 63;
    const int lr  = l & 15, lk = l >> 4;
    const int hcol = w * 16 + lr;

    __shared__ __align__(16) char lds[LDSZ];

    // ---- loop-invariant register state ----
    v4i   B8[4][2];
    bfrag Bx[4];
    facc  bsp[4];
    float sw4[4];
#pragma unroll
    for (int q = 0; q < 4; ++q) {
        const int n = q * H_ + hcol;
#pragma unroll
        for (int ks = 0; ks < 2; ++ks)
            B8[q][ks] = *(const v4i*)(w8 + n * 128 + ks * 64 + lk * 16);
        Bx[q] = *(const bfrag*)(wih_bf + n * 32 + lk * 8);
        const float b = bias[n];
        bsp[q] = (facc){b, b, b, b};
        sw4[q] = sw[n];
    }
#pragma unroll
    for (int q = 0; q < 4; ++q) {          // pin: forbid in-loop remat
        asm volatile("" : "+v"(B8[q][0]));
        asm volatile("" : "+v"(B8[q][1]));
        asm volatile("" : "+v"(Bx[q]));
        asm volatile("" : "+v"(bsp[q]));
    }

    // lane offsets (broadcast rows: A row index = lr&1 duplicates across lanes)
    const int r2  = lr & 1;
    const int hrd = r2 * 128 + ((lk * 16) ^ (r2 << 4));
    const int xrd = r2 * 64 + lk * 16;
    // epilogue chain ownership: (g,s) = (lk>>1, lk&1), col = hcol
    const bool b0 = (lk & 1) != 0;
    const bool b1 = (lk & 2) != 0;
    const int wg = lk >> 1, ws = lk & 1;
    const int wbase = SH0 + wg * 512 + ws * 128 + (hcol ^ (ws << 4));

    // staging: thread -> (group, tl, seq, k-half); 512 slots = 512 threads
    const int sg  = tid >> 8;              // 0 = A, 1 = B
    const int ss  = tid & 255;
    const int stl = ss >> 2, sseq = (ss >> 1) & 1, skb = ss & 1;
    const int seqg = m0 + sg * 2 + sseq;
    const int bb = seqg / N_, nn = seqg % N_;
    const float* xq = x + (((size_t)bb * T_ + stl) * N_ + nn) * F_ + skb * 8;
    const int sbyte = (sg ? SXB : SXA) + stl * 128 + sseq * 64 + skb * 16;

    // ---- init: zero LDS (x pad stays 0; h[parity 0] = initial state 0) ----
    for (int i = tid; i < LDSZ / 4; i += 512) ((int*)lds)[i] = 0;
    float4 p0 = *(const float4*)xq, p1 = *(const float4*)(xq + 4);

    float cc = 0.0f;
    facc  xaccA[4], xaccB[4];
    bar();

#pragma unroll 1
    for (int chunk = 0; chunk < T_ / TCH; ++chunk) {
        // stage prefetched x chunk
        {
            uint4 o;
            o.x = cvt_pk_bf16(p0.x, p0.y); o.y = cvt_pk_bf16(p0.z, p0.w);
            o.z = cvt_pk_bf16(p1.x, p1.y); o.w = cvt_pk_bf16(p1.z, p1.w);
            *(uint4*)(lds + sbyte) = o;
        }
        if (chunk + 1 < T_ / TCH) {        // next chunk loads stay in flight
            xq += TCH * N_ * F_;
            p0 = *(const float4*)xq; p1 = *(const float4*)(xq + 4);
        }
        bar();

        // preamble: xacc for tl=0
        {
            const bfrag axA = *(const bfrag*)(lds + SXA + xrd);
            const bfrag axB = *(const bfrag*)(lds + SXB + xrd);
#pragma unroll
            for (int q = 0; q < 4; ++q)
                xaccA[q] = __builtin_amdgcn_mfma_f32_16x16x32_bf16(axA, Bx[q], bsp[q], 0, 0, 0);
#pragma unroll
            for (int q = 0; q < 4; ++q)
                xaccB[q] = __builtin_amdgcn_mfma_f32_16x16x32_bf16(axB, Bx[q], bsp[q], 0, 0, 0);
        }

#pragma unroll 1
        for (int tl = 0; tl < TCH; tl += 2) {
            lstm_step<0, true>(lds, tl, B8, Bx, bsp, sw4, xaccA, xaccB, cc,
                               hrd, xrd, wbase, b0, b1);
            if (tl + 2 < TCH)
                lstm_step<1, true>(lds, tl + 1, B8, Bx, bsp, sw4, xaccA, xaccB, cc,
                                   hrd, xrd, wbase, b0, b1);
            else
                lstm_step<1, false>(lds, tl + 1, B8, Bx, bsp, sw4, xaccA, xaccB, cc,
                                    hrd, xrd, wbase, b0, b1);
        }
    }
    bar();   // final h writes (parity 0 bufs) -> readout

    // readout: h8 -> bf16 (4 seqs x 128 cols; 1 elem/thread)
    {
        const int g = tid >> 8, s = (tid >> 7) & 1, c = tid & 127;
        const int addr = SH0 + g * 512 + s * 128 + (c ^ (s << 4));
        const signed char v = *(const signed char*)(lds + addr);
        h_out[(size_t)(m0 + g * 2 + s) * H_ + c] = f2bf((float)v * (1.0f / 127.0f));
    }
}

// ---------------------------------------------------------------------------
// Head kernel: one block per batch element b. GCN + linears + sigmoid.
// ---------------------------------------------------------------------------
__global__ __launch_bounds__(256) void head_kernel(
    const float* __restrict__ adj,
    const float* __restrict__ W_gcn, const float* __restrict__ b_gcn,
    const float* __restrict__ W_out, const float* __restrict__ b_out,
    const float* __restrict__ W_lin1, const float* __restrict__ b_lin1,
    const unsigned short* __restrict__ h_in,   // [896][128] bf16
    float* __restrict__ out)                   // [B, 28]
{
    const int b   = blockIdx.x;
    const int tid = threadIdx.x;

    __shared__ float s_A[N_][N_];
    __shared__ float s_d[N_];
    __shared__ float s_h[N_][H_];
    __shared__ float s_xg[N_][H_];
    __shared__ float s_g1[N_][64];
    __shared__ float s_s[N_];

    for (int idx = tid; idx < N_ * H_; idx += 256)
        s_h[idx >> 7][idx & 127] = bf2f(h_in[(size_t)b * N_ * H_ + idx]);

    if (tid < N_) {
        float sum = 0.0f;
        for (int j = 0; j < N_; ++j)
            sum += adj[tid * N_ + j] + (tid == j ? 1.0f : 0.0f);
        s_d[tid] = rsqrtf(sum);
    }
    __syncthreads();

    if (tid < N_ * N_) {
        const int i = tid / N_, j = tid % N_;
        const float a = adj[i * N_ + j] + (i == j ? 1.0f : 0.0f);
        s_A[i][j] = s_d[i] * a * s_d[j];
    }
    __syncthreads();

    for (int idx = tid; idx < N_ * H_; idx += 256) {
        const int i = idx >> 7, k = idx & 127;
        float acc = 0.0f;
#pragma unroll
        for (int j = 0; j < N_; ++j) acc += s_A[i][j] * s_h[j][k];
        s_xg[i][k] = acc;
    }
    __syncthreads();

    for (int idx = tid; idx < N_ * 64; idx += 256) {
        const int i = idx >> 6, q = idx & 63;
        float a0 = 0.f, a1 = 0.f, a2 = 0.f, a3 = 0.f;
#pragma unroll
        for (int k = 0; k < H_; k += 4) {
            a0 += s_xg[i][k+0] * W_gcn[q * H_ + k+0];
            a1 += s_xg[i][k+1] * W_gcn[q * H_ + k+1];
            a2 += s_xg[i][k+2] * W_gcn[q * H_ + k+2];
            a3 += s_xg[i][k+3] * W_gcn[q * H_ + k+3];
        }
        const float acc = b_gcn[q] + ((a0 + a1) + (a2 + a3));
        s_g1[i][q] = fmaxf(acc, 0.0f);
    }
    __syncthreads();

    if (tid < N_) {
        float acc = b_out[0];
#pragma unroll
        for (int q = 0; q < 64; ++q) acc += s_g1[tid][q] * W_out[q];
        s_s[tid] = acc;
    }
    __syncthreads();

    if (tid < 28) {
        float acc = b_lin1[tid];
#pragma unroll
        for (int i = 0; i < N_; ++i) acc += s_s[i] * W_lin1[tid * N_ + i];
        out[b * 28 + tid] = 1.0f / (1.0f + __expf(-acc));
    }
}

extern "C" void kernel_launch(void* const* d_in, const int* in_sizes, int n_in,
                              void* d_out, int out_size, void* d_ws, size_t ws_size,
                              hipStream_t stream) {
    const float* x      = (const float*)d_in[0];
    const float* adj    = (const float*)d_in[1];
    const float* W_ih   = (const float*)d_in[2];
    const float* W_hh   = (const float*)d_in[3];
    const float* b_ih   = (const float*)d_in[4];
    const float* b_hh   = (const float*)d_in[5];
    const float* W_gcn  = (const float*)d_in[6];
    const float* b_gcn  = (const float*)d_in[7];
    const float* W_out  = (const float*)d_in[8];
    const float* b_out  = (const float*)d_in[9];
    const float* W_lin1 = (const float*)d_in[10];
    const float* b_lin1 = (const float*)d_in[11];
    float* out = (float*)d_out;

    // workspace layout (bytes): total 333824
    char* ws = (char*)d_ws;
    signed char*    w8     = (signed char*)(ws);              // 512*128   =  65536
    short*          wih_bf = (short*)(ws + 65536);            // 512*32*2  =  32768
    float*          bias   = (float*)(ws + 98304);            // 512*4     =   2048
    float*          sw     = (float*)(ws + 100352);           // 512*4     =   2048
    float*          inv127 = (float*)(ws + 102400);           // 512*4     =   2048
    unsigned short* h_last = (unsigned short*)(ws + 104448);  // 896*128*2 = 229376

    prep1_kernel<<<1, 512, 0, stream>>>(W_hh, b_ih, b_hh, inv127, sw, bias);
    prep2_kernel<<<128, 512, 0, stream>>>(W_hh, W_ih, inv127, w8, wih_bf);
    lstm_kernel<<<NBLK, 512, 0, stream>>>(x, w8, wih_bf, bias, sw, h_last);
    head_kernel<<<B_, 256, 0, stream>>>(adj, W_gcn, b_gcn, W_out, b_out,
                                        W_lin1, b_lin1, h_last, out);
}

// Round 10
// 258.524 us; speedup vs baseline: 4.3944x; 1.4826x over previous
//
#include <hip/hip_runtime.h>
#include <hip/hip_bf16.h>

#define B_   64
#define T_   512
#define N_   14
#define F_   16
#define H_   128
#define G4_  512
#define TCH  64     // timesteps staged per LDS chunk
#define MBLK 4      // sequences per block (4 row-groups of 1)
#define NBLK 224

typedef __attribute__((ext_vector_type(8))) short bfrag;  // 8 bf16
typedef __attribute__((ext_vector_type(4))) float facc;   // fp32 acc
typedef __attribute__((ext_vector_type(4))) int   v4i;    // i8x16 / i32x4

#define L2E   1.4426950408889634f
#define L2E2  2.8853900817779268f

// LDS byte offsets
#define SX   0      // x: [64 tl][4 seq][32 k] bf16 (k>=16 zero) = 16 KB
#define SH   16384  // h8: [2 parity][8 kslice][4 group][16B] = 1 KB
#define LDSZ 17408

__device__ __forceinline__ short f2bf(float f) {
    unsigned u = __builtin_bit_cast(unsigned, f);
    return (short)((u + 0x7FFFu + ((u >> 16) & 1u)) >> 16);
}
__device__ __forceinline__ float bf2f(unsigned short s) {
    return __builtin_bit_cast(float, (unsigned)s << 16);
}
__device__ __forceinline__ unsigned cvt_pk_bf16(float a, float b) {
    unsigned r;
    asm("v_cvt_pk_bf16_f32 %0, %1, %2" : "=v"(r) : "v"(a), "v"(b));
    return r;
}
// i8 MFMA (validated rounds 6-9)
__device__ __forceinline__ v4i mfma_i8(v4i a, v4i b, v4i c) {
    v4i d;
    asm("v_mfma_i32_16x16x64_i8 %0, %1, %2, %3"
        : "=&v"(d) : "v"(a), "v"(b), "v"(c));
    return d;
}
// lgkm-only barrier: global prefetch loads stay in flight across barriers.
__device__ __forceinline__ void bar() {
    asm volatile("s_waitcnt lgkmcnt(0)" ::: "memory");
    __builtin_amdgcn_s_barrier();
    asm volatile("" ::: "memory");
}

// ---------------------------------------------------------------------------
// prep1: per-gate-row max of W_hh -> i8 scale; fused biases; log2e pre-scale
// (2x for the g-gate section) so the epilogue uses native exp2.
// ---------------------------------------------------------------------------
__global__ void prep1_kernel(const float* __restrict__ W_hh,
                             const float* __restrict__ b_ih, const float* __restrict__ b_hh,
                             float* __restrict__ inv127, float* __restrict__ sw,
                             float* __restrict__ bias) {
    const int g = threadIdx.x;            // 0..511
    float mx = 0.0f;
    for (int k = 0; k < H_; ++k) mx = fmaxf(mx, fabsf(W_hh[g * H_ + k]));
    const float sc = (g >= 256 && g < 384) ? L2E2 : L2E;
    inv127[g] = 127.0f / mx;
    sw[g]     = mx * sc * (1.0f / 16129.0f);   // mx/127 * 1/127 * log2e-scale
    bias[g]   = (b_ih[g] + b_hh[g]) * sc;
}

// ---------------------------------------------------------------------------
// prep2: W_hh -> i8 (row-scaled); W_ih -> bf16 (log2e-scaled, K padded 16->32)
// ---------------------------------------------------------------------------
__global__ void prep2_kernel(const float* __restrict__ W_hh, const float* __restrict__ W_ih,
                             const float* __restrict__ inv127,
                             signed char* __restrict__ w8, short* __restrict__ wih_bf) {
    const int i = blockIdx.x * blockDim.x + threadIdx.x;   // 0..65535
    if (i < G4_ * H_)
        w8[i] = (signed char)(int)rintf(W_hh[i] * inv127[i >> 7]);
    if (i < G4_ * 32) {
        const int n = i >> 5, k = i & 31;
        const float sc = (n >= 256 && n < 384) ? L2E2 : L2E;
        wih_bf[i] = (k < F_) ? f2bf(W_ih[n * F_ + k] * sc) : (short)0;
    }
}

// ---------------------------------------------------------------------------
// One timestep for ALL 4 seq-groups; single barrier. Rows 4g..4g+3 of the
// MFMA tile hold group g (duplicated); lane (lk,lr) reg 0 = (group lk, col
// hcol) -> zero-select, zero-duplication epilogue. P = parity (read h[P],
// write h[P^1]). PREF: compute next step's xacc (reads SX only).
// ---------------------------------------------------------------------------
template<int P, bool PREF>
__device__ __forceinline__ void lstm_step(char* lds, int tl,
    const v4i (&B8)[4][2], const bfrag (&Bx)[4], const facc (&bsp)[4],
    const float (&sw4)[4], facc (&xacc)[4], float& cc,
    int hrd, int xrd, int wboff)
{
    bar();
    const char* hb = lds + SH + P * 512;
    const v4i a0 = *(const v4i*)(hb + hrd);          // kslice lk   (k 16lk..)
    const v4i a1 = *(const v4i*)(hb + hrd + 256);    // kslice lk+4 (k 64+16lk)

    const v4i z4 = (v4i){0, 0, 0, 0};
    v4i acc[4];
#pragma unroll
    for (int q = 0; q < 4; ++q) acc[q] = mfma_i8(a0, B8[q][0], z4);
#pragma unroll
    for (int q = 0; q < 4; ++q) acc[q] = mfma_i8(a1, B8[q][1], acc[q]);

    // z[q]: reg 0 = row 4lk = group lk, col hcol. xacc carries bias.
    float z[4];
#pragma unroll
    for (int q = 0; q < 4; ++q)
        z[q] = (float)acc[q][0] * sw4[q] + xacc[q][0];

    // ---- single gate chain per lane ----
    const float ea = exp2f(-z[0]);
    const float ef = exp2f(-z[1]);
    const float eo = exp2f(-z[3]);
    const float eg = exp2f(-fabsf(z[2]));
    const float d1 = (1.0f + ea) * (1.0f + eg);
    const float d2 = 1.0f + ef;
    const float rP = __builtin_amdgcn_rcpf(d1 * d2);       // shared rcp
    const float ig = __builtin_copysignf((1.0f - eg) * (rP * d2), z[2]);
    cc = (rP * d1) * cc + ig;
    const float ec = exp2f(-L2E2 * fabsf(cc));
    const float hv = __builtin_copysignf(
        (1.0f - ec) * __builtin_amdgcn_rcpf((1.0f + eo) * (1.0f + ec)), cc);
    *(signed char*)(lds + SH + (P ^ 1) * 512 + wboff) =
        (signed char)(int)rintf(hv * 127.0f);

    if (PREF) {   // next step's x-contribution (SX-only; off the h-chain)
        const bfrag ax = *(const bfrag*)(lds + SX + (tl + 1) * 256 + xrd);
#pragma unroll
        for (int q = 0; q < 4; ++q)
            xacc[q] = __builtin_amdgcn_mfma_f32_16x16x32_bf16(ax, Bx[q], bsp[q], 0, 0, 0);
    }
}

// ---------------------------------------------------------------------------
// LSTM: 224 blocks x 512 thr; block owns 4 seqs as 4 row-groups of the tile.
// Wave w owns gate-cols {q*128 + 16w .. +16} for all gates.
// ---------------------------------------------------------------------------
__global__ __launch_bounds__(512, 2) void lstm_kernel(
    const float* __restrict__ x,            // [B, T, N, F] fp32
    const signed char* __restrict__ w8,     // [512][128] i8
    const short* __restrict__ wih_bf,       // [512][32] bf16
    const float* __restrict__ bias,         // [512] (log2e-scaled)
    const float* __restrict__ sw,           // [512] descale * log2e
    unsigned short* __restrict__ h_out)     // [896][128] bf16
{
    const int m0  = blockIdx.x * MBLK;
    const int tid = threadIdx.x;
    const int w   = tid >> 6, l = tid & 63;
    const int lr  = l & 15, lk = l >> 4;
    const int hcol = w * 16 + lr;

    __shared__ __align__(16) char lds[LDSZ];

    // ---- loop-invariant register state ----
    v4i   B8[4][2];
    bfrag Bx[4];
    facc  bsp[4];
    float sw4[4];
#pragma unroll
    for (int q = 0; q < 4; ++q) {
        const int n = q * H_ + hcol;
#pragma unroll
        for (int ks = 0; ks < 2; ++ks)
            B8[q][ks] = *(const v4i*)(w8 + n * 128 + ks * 64 + lk * 16);
        Bx[q] = *(const bfrag*)(wih_bf + n * 32 + lk * 8);
        const float b = bias[n];
        bsp[q] = (facc){b, b, b, b};
        sw4[q] = sw[n];
    }
#pragma unroll
    for (int q = 0; q < 4; ++q) {          // pin: forbid in-loop remat
        asm volatile("" : "+v"(B8[q][0]));
        asm volatile("" : "+v"(B8[q][1]));
        asm volatile("" : "+v"(Bx[q]));
        asm volatile("" : "+v"(bsp[q]));
    }

    // lane LDS offsets
    // h read (A-frag): row lr -> group lr>>2; k-slice (ks*4+lk)*16.
    //   layout: [kslice s][group][16B] -> addr = s*64 + g*16 (+ks*256 via +256)
    const int hrd = lk * 64 + (lr >> 2) * 16;
    // x read: [tl][group][32k bf16] -> addr = tl*256 + g*64 + lk*16
    const int xrd = (lr >> 2) * 64 + lk * 16;
    // h write: lane owns (group lk, col hcol); k index = hcol
    //   addr = (hcol>>4)*64 + lk*16 + (hcol&15) = w*64 + lk*16 + lr
    const int wboff = w * 64 + lk * 16 + lr;

    // staging: thread -> (tl 0..63, seq 0..3, k-half); 512 slots = 512 threads
    const int skb = tid & 1, sseq = (tid >> 1) & 3, stl = tid >> 3;
    const int seqg = m0 + sseq;
    const int bb = seqg / N_, nn = seqg % N_;
    const float* xq = x + (((size_t)bb * T_ + stl) * N_ + nn) * F_ + skb * 8;
    const int sbyte = SX + stl * 256 + sseq * 64 + skb * 16;

    // ---- init: zero LDS (x pad stays 0; h[parity 0] = initial state 0) ----
    for (int i = tid; i < LDSZ / 4; i += 512) ((int*)lds)[i] = 0;
    float4 p0 = *(const float4*)xq, p1 = *(const float4*)(xq + 4);

    float cc = 0.0f;
    facc  xacc[4];
    bar();

#pragma unroll 1
    for (int chunk = 0; chunk < T_ / TCH; ++chunk) {
        // stage prefetched x chunk
        {
            uint4 o;
            o.x = cvt_pk_bf16(p0.x, p0.y); o.y = cvt_pk_bf16(p0.z, p0.w);
            o.z = cvt_pk_bf16(p1.x, p1.y); o.w = cvt_pk_bf16(p1.z, p1.w);
            *(uint4*)(lds + sbyte) = o;
        }
        if (chunk + 1 < T_ / TCH) {        // next chunk loads stay in flight
            xq += TCH * N_ * F_;
            p0 = *(const float4*)xq; p1 = *(const float4*)(xq + 4);
        }
        bar();

        // preamble: xacc for tl=0
        {
            const bfrag ax = *(const bfrag*)(lds + SX + xrd);
#pragma unroll
            for (int q = 0; q < 4; ++q)
                xacc[q] = __builtin_amdgcn_mfma_f32_16x16x32_bf16(ax, Bx[q], bsp[q], 0, 0, 0);
        }

#pragma unroll 1
        for (int tl = 0; tl < TCH; tl += 2) {
            lstm_step<0, true>(lds, tl, B8, Bx, bsp, sw4, xacc, cc,
                               hrd, xrd, wboff);
            if (tl + 2 < TCH)
                lstm_step<1, true>(lds, tl + 1, B8, Bx, bsp, sw4, xacc, cc,
                                   hrd, xrd, wboff);
            else
                lstm_step<1, false>(lds, tl + 1, B8, Bx, bsp, sw4, xacc, cc,
                                    hrd, xrd, wboff);
        }
    }
    bar();   // final h writes (parity 0 buf) -> readout

    // readout: h8 -> bf16 (4 seqs x 128 cols; 1 elem/thread)
    {
        const int g = tid >> 7, c = tid & 127;
        const int addr = SH + (c >> 4) * 64 + g * 16 + (c & 15);
        const signed char v = *(const signed char*)(lds + addr);
        h_out[(size_t)(m0 + g) * H_ + c] = f2bf((float)v * (1.0f / 127.0f));
    }
}

// ---------------------------------------------------------------------------
// Head kernel: one block per batch element b. GCN + linears + sigmoid.
// ---------------------------------------------------------------------------
__global__ __launch_bounds__(256) void head_kernel(
    const float* __restrict__ adj,
    const float* __restrict__ W_gcn, const float* __restrict__ b_gcn,
    const float* __restrict__ W_out, const float* __restrict__ b_out,
    const float* __restrict__ W_lin1, const float* __restrict__ b_lin1,
    const unsigned short* __restrict__ h_in,   // [896][128] bf16
    float* __restrict__ out)                   // [B, 28]
{
    const int b   = blockIdx.x;
    const int tid = threadIdx.x;

    __shared__ float s_A[N_][N_];
    __shared__ float s_d[N_];
    __shared__ float s_h[N_][H_];
    __shared__ float s_xg[N_][H_];
    __shared__ float s_g1[N_][64];
    __shared__ float s_s[N_];

    for (int idx = tid; idx < N_ * H_; idx += 256)
        s_h[idx >> 7][idx & 127] = bf2f(h_in[(size_t)b * N_ * H_ + idx]);

    if (tid < N_) {
        float sum = 0.0f;
        for (int j = 0; j < N_; ++j)
            sum += adj[tid * N_ + j] + (tid == j ? 1.0f : 0.0f);
        s_d[tid] = rsqrtf(sum);
    }
    __syncthreads();

    if (tid < N_ * N_) {
        const int i = tid / N_, j = tid % N_;
        const float a = adj[i * N_ + j] + (i == j ? 1.0f : 0.0f);
        s_A[i][j] = s_d[i] * a * s_d[j];
    }
    __syncthreads();

    for (int idx = tid; idx < N_ * H_; idx += 256) {
        const int i = idx >> 7, k = idx & 127;
        float acc = 0.0f;
#pragma unroll
        for (int j = 0; j < N_; ++j) acc += s_A[i][j] * s_h[j][k];
        s_xg[i][k] = acc;
    }
    __syncthreads();

    for (int idx = tid; idx < N_ * 64; idx += 256) {
        const int i = idx >> 6, q = idx & 63;
        float a0 = 0.f, a1 = 0.f, a2 = 0.f, a3 = 0.f;
#pragma unroll
        for (int k = 0; k < H_; k += 4) {
            a0 += s_xg[i][k+0] * W_gcn[q * H_ + k+0];
            a1 += s_xg[i][k+1] * W_gcn[q * H_ + k+1];
            a2 += s_xg[i][k+2] * W_gcn[q * H_ + k+2];
            a3 += s_xg[i][k+3] * W_gcn[q * H_ + k+3];
        }
        const float acc = b_gcn[q] + ((a0 + a1) + (a2 + a3));
        s_g1[i][q] = fmaxf(acc, 0.0f);
    }
    __syncthreads();

    if (tid < N_) {
        float acc = b_out[0];
#pragma unroll
        for (int q = 0; q < 64; ++q) acc += s_g1[tid][q] * W_out[q];
        s_s[tid] = acc;
    }
    __syncthreads();

    if (tid < 28) {
        float acc = b_lin1[tid];
#pragma unroll
        for (int i = 0; i < N_; ++i) acc += s_s[i] * W_lin1[tid * N_ + i];
        out[b * 28 + tid] = 1.0f / (1.0f + __expf(-acc));
    }
}

extern "C" void kernel_launch(void* const* d_in, const int* in_sizes, int n_in,
                              void* d_out, int out_size, void* d_ws, size_t ws_size,
                              hipStream_t stream) {
    const float* x      = (const float*)d_in[0];
    const float* adj    = (const float*)d_in[1];
    const float* W_ih   = (const float*)d_in[2];
    const float* W_hh   = (const float*)d_in[3];
    const float* b_ih   = (const float*)d_in[4];
    const float* b_hh   = (const float*)d_in[5];
    const float* W_gcn  = (const float*)d_in[6];
    const float* b_gcn  = (const float*)d_in[7];
    const float* W_out  = (const float*)d_in[8];
    const float* b_out  = (const float*)d_in[9];
    const float* W_lin1 = (const float*)d_in[10];
    const float* b_lin1 = (const float*)d_in[11];
    float* out = (float*)d_out;

    // workspace layout (bytes): total 333824
    char* ws = (char*)d_ws;
    signed char*    w8     = (signed char*)(ws);              // 512*128   =  65536
    short*          wih_bf = (short*)(ws + 65536);            // 512*32*2  =  32768
    float*          bias   = (float*)(ws + 98304);            // 512*4     =   2048
    float*          sw     = (float*)(ws + 100352);           // 512*4     =   2048
    float*          inv127 = (float*)(ws + 102400);           // 512*4     =   2048
    unsigned short* h_last = (unsigned short*)(ws + 104448);  // 896*128*2 = 229376

    prep1_kernel<<<1, 512, 0, stream>>>(W_hh, b_ih, b_hh, inv127, sw, bias);
    prep2_kernel<<<128, 512, 0, stream>>>(W_hh, W_ih, inv127, w8, wih_bf);
    lstm_kernel<<<NBLK, 512, 0, stream>>>(x, w8, wih_bf, bias, sw, h_last);
    head_kernel<<<B_, 256, 0, stream>>>(adj, W_gcn, b_gcn, W_out, b_out,
                                        W_lin1, b_lin1, h_last, out);
}